// Round 9
// baseline (750.969 us; speedup 1.0000x reference)
//
#include <hip/hip_runtime.h>
#include <hip/hip_bf16.h>

#define N_NODES 3136
#define NB 8
#define DIMF 384

// ws layout (bytes):
//   norms : float[25088]   @ 0        (100352)
//   sq    : float[25088]   @ 100352   (100352)
//   pe    : float[301056]  @ 200704   (1204224)   784 x 384
//   RP    : float[614656]  @ 1404928  (2458624)   784 x 784
//   dist  : float[2458624] @ 3863552  (9834496)   4 x 784 x 784 per-batch reuse
// total 13,698,048 B

// ---- pe table: replica of numpy f32 _sincos_1d ------------------------------
__global__ void pe_kernel(float* __restrict__ pe) {
    int p = blockIdx.x;          // 0..783, p = r*28 + c, positions (2r, 2c)
    int d = threadIdx.x;         // 0..95
    int r = p / 28, c = p % 28;
    float wpos = (float)(2 * c);     // emb_h uses grid[0] = W coords
    float hpos = (float)(2 * r);
    float wexp = (float)d / 96.0f;                    // f32 divide, as np
    float t = (float)pow(10000.0, (double)wexp);      // cr-f32 of 10000**w
    float om = 1.0f / t;                              // f32 divide, as np
    float aw = wpos * om;                             // f32 product (einsum)
    float ah = hpos * om;
    pe[(size_t)p * DIMF + d]       = (float)sin((double)aw);  // cr-f32 sin(f32 arg)
    pe[(size_t)p * DIMF + 96 + d]  = (float)cos((double)aw);
    pe[(size_t)p * DIMF + 192 + d] = (float)sin((double)ah);
    pe[(size_t)p * DIMF + 288 + d] = (float)cos((double)ah);
}

// ---- norm & sq: numpy pairwise-sum replica (384=(96+96)+(96+96), 8-acc base) -
__global__ __launch_bounds__(256) void norm_sq_kernel(const float* __restrict__ x,
                                                      float* __restrict__ norms,
                                                      float* __restrict__ sq) {
    int tid = threadIdx.x;
    int g = blockIdx.x * 32 + (tid >> 3);     // node 0..25087
    int lane = tid & 7;
    const float* row = x + (size_t)g * DIMF;
    float p4[4];
    #pragma unroll
    for (int b = 0; b < 4; ++b) {
        const float* blk = row + 96 * b;
        float t0 = blk[lane];
        float r = __fmul_rn(t0, t0);
        for (int i = 8; i < 96; i += 8) {
            float t = blk[i + lane];
            r = __fadd_rn(r, __fmul_rn(t, t));
        }
        r = __fadd_rn(r, __shfl_xor(r, 1));   // (r0+r1) etc.
        r = __fadd_rn(r, __shfl_xor(r, 2));   // ((r0+r1)+(r2+r3)) etc.
        r = __fadd_rn(r, __shfl_xor(r, 4));   // full 8-acc combine
        p4[b] = r;
    }
    float s = __fadd_rn(__fadd_rn(p4[0], p4[1]), __fadd_rn(p4[2], p4[3]));
    float n = fmaxf(__fsqrt_rn(s), 1e-12f);   // np: sqrt f32, clip
    #pragma unroll
    for (int b = 0; b < 4; ++b) {
        const float* blk = row + 96 * b;
        float t0 = __fdiv_rn(blk[lane], n);   // f32 divide, as np broadcast
        float r = __fmul_rn(t0, t0);
        for (int i = 8; i < 96; i += 8) {
            float t = __fdiv_rn(blk[i + lane], n);
            r = __fadd_rn(r, __fmul_rn(t, t));
        }
        r = __fadd_rn(r, __shfl_xor(r, 1));
        r = __fadd_rn(r, __shfl_xor(r, 2));
        r = __fadd_rn(r, __shfl_xor(r, 4));
        p4[b] = r;
    }
    float s2 = __fadd_rn(__fadd_rn(p4[0], p4[1]), __fadd_rn(p4[2], p4[3]));
    if (lane == 0) {
        int b = g / N_NODES, loc = g % N_NODES;
        int r = loc / 56, c = loc % 56;
        int cls = (r & 1) * 2 + (c & 1);
        int m = (r >> 1) * 28 + (c >> 1);
        norms[g] = n;
        sq[(size_t)(b * 4 + cls) * 784 + m] = s2;
    }
}

// ---- RP: OpenBLAS-sgemm replica (sequential-k f32 FMA) + ref's f32 chain ----
__global__ __launch_bounds__(256) void rp_gemm(const float* __restrict__ pe,
                                               float* __restrict__ RP) {
    int brow = blockIdx.y * 64, bcol = blockIdx.x * 64;
    __shared__ float As[64][36], Bs[64][36];
    int t = threadIdx.x;
    int tx = t & 15, ty = t >> 4;
    float acc[4][4] = {{0.f}};
    for (int k0 = 0; k0 < DIMF; k0 += 32) {
        __syncthreads();
        #pragma unroll
        for (int p = 0; p < 2; ++p) {
            int f = t + 256 * p;
            int m = f >> 3, kq = f & 7;
            float4 v = make_float4(0.f, 0.f, 0.f, 0.f);
            int rowi = brow + m;
            if (rowi < 784) v = *(const float4*)(pe + (size_t)rowi * DIMF + k0 + kq * 4);
            *(float4*)&As[m][kq * 4] = v;
            float4 w = make_float4(0.f, 0.f, 0.f, 0.f);
            int coli = bcol + m;
            if (coli < 784) w = *(const float4*)(pe + (size_t)coli * DIMF + k0 + kq * 4);
            *(float4*)&Bs[m][kq * 4] = w;
        }
        __syncthreads();
        #pragma unroll 4
        for (int k = 0; k < 32; ++k) {          // ascending k, single FMA chain
            float ra[4], rb[4];
            #pragma unroll
            for (int ii = 0; ii < 4; ++ii) ra[ii] = As[ty + 16 * ii][k];
            #pragma unroll
            for (int jj = 0; jj < 4; ++jj) rb[jj] = Bs[tx + 16 * jj][k];
            #pragma unroll
            for (int ii = 0; ii < 4; ++ii)
                #pragma unroll
                for (int jj = 0; jj < 4; ++jj)
                    acc[ii][jj] = __fmaf_rn(ra[ii], rb[jj], acc[ii][jj]);
        }
    }
    #pragma unroll
    for (int ii = 0; ii < 4; ++ii) {
        int i = brow + ty + 16 * ii;
        if (i >= 784) continue;
        #pragma unroll
        for (int jj = 0; jj < 4; ++jj) {
            int j = bcol + tx + 16 * jj;
            if (j >= 784) continue;
            float X = acc[ii][jj];
            float num = __fmul_rn(2.0f, X);         // np: 2.0 * M
            float q = __fdiv_rn(num, 384.0f);       // np: / DIM
            RP[(size_t)i * 784 + j] = -q;           // np: unary negate
        }
    }
}

// ---- dist: np.einsum replica — 4-lane SSE mul+add partials, hadd tree -------
__global__ __launch_bounds__(256) void dist_gemm(const float* __restrict__ x,
                                                 const float* __restrict__ norms,
                                                 const float* __restrict__ sq,
                                                 const float* __restrict__ RP,
                                                 float* __restrict__ dist, int b) {
    int cls = blockIdx.z;
    int brow = blockIdx.y * 64, bcol = blockIdx.x * 64;
    int oh = cls >> 1, ow = cls & 1;
    __shared__ float As[64][36], Bs[64][36];
    int t = threadIdx.x;
    int tx = t & 15, ty = t >> 4;
    float4 acc[4][4];
    #pragma unroll
    for (int ii = 0; ii < 4; ++ii)
        #pragma unroll
        for (int jj = 0; jj < 4; ++jj) acc[ii][jj] = make_float4(0.f, 0.f, 0.f, 0.f);
    for (int k0 = 0; k0 < DIMF; k0 += 32) {
        __syncthreads();
        #pragma unroll
        for (int p = 0; p < 2; ++p) {
            int f = t + 256 * p;
            int m = f >> 3, kq = f & 7;
            {
                int rowi = brow + m;
                float4 v = make_float4(0.f, 0.f, 0.f, 0.f);
                if (rowi < 784) {
                    int g = b * N_NODES + (oh + 2 * (rowi / 28)) * 56 + (ow + 2 * (rowi % 28));
                    float4 a = *(const float4*)(x + (size_t)g * DIMF + k0 + kq * 4);
                    float n = norms[g];
                    v.x = __fdiv_rn(a.x, n); v.y = __fdiv_rn(a.y, n);
                    v.z = __fdiv_rn(a.z, n); v.w = __fdiv_rn(a.w, n);   // = np xn bits
                }
                *(float4*)&As[m][kq * 4] = v;
            }
            {
                int coli = bcol + m;
                float4 v = make_float4(0.f, 0.f, 0.f, 0.f);
                if (coli < 784) {
                    int g = b * N_NODES + (oh + 2 * (coli / 28)) * 56 + (ow + 2 * (coli % 28));
                    float4 a = *(const float4*)(x + (size_t)g * DIMF + k0 + kq * 4);
                    float n = norms[g];
                    v.x = __fdiv_rn(a.x, n); v.y = __fdiv_rn(a.y, n);
                    v.z = __fdiv_rn(a.z, n); v.w = __fdiv_rn(a.w, n);
                }
                *(float4*)&Bs[m][kq * 4] = v;
            }
        }
        __syncthreads();
        // np.einsum f32 contig SIMD: lane l accumulates k = 4i+l, mul then add
        #pragma unroll 2
        for (int k4 = 0; k4 < 32; k4 += 4) {
            float4 ra[4], rb[4];
            #pragma unroll
            for (int ii = 0; ii < 4; ++ii) ra[ii] = *(float4*)&As[ty + 16 * ii][k4];
            #pragma unroll
            for (int jj = 0; jj < 4; ++jj) rb[jj] = *(float4*)&Bs[tx + 16 * jj][k4];
            #pragma unroll
            for (int ii = 0; ii < 4; ++ii)
                #pragma unroll
                for (int jj = 0; jj < 4; ++jj) {
                    acc[ii][jj].x = __fadd_rn(acc[ii][jj].x, __fmul_rn(ra[ii].x, rb[jj].x));
                    acc[ii][jj].y = __fadd_rn(acc[ii][jj].y, __fmul_rn(ra[ii].y, rb[jj].y));
                    acc[ii][jj].z = __fadd_rn(acc[ii][jj].z, __fmul_rn(ra[ii].z, rb[jj].z));
                    acc[ii][jj].w = __fadd_rn(acc[ii][jj].w, __fmul_rn(ra[ii].w, rb[jj].w));
                }
        }
    }
    int sqb = (b * 4 + cls) * 784;
    #pragma unroll
    for (int ii = 0; ii < 4; ++ii) {
        int i = brow + ty + 16 * ii;
        if (i >= 784) continue;
        float sqi = sq[sqb + i];
        #pragma unroll
        for (int jj = 0; jj < 4; ++jj) {
            int j = bcol + tx + 16 * jj;
            if (j >= 784) continue;
            float4 a = acc[ii][jj];
            // SSE3 hadd tree: (p0+p1) + (p2+p3)
            float X  = __fadd_rn(__fadd_rn(a.x, a.y), __fadd_rn(a.z, a.w));
            float t1 = __fadd_rn(sqi, sq[sqb + j]);            // sq_i + sq_j
            float pd = __fsub_rn(t1, __fmul_rn(2.0f, X));      // - 2*dot
            float v  = __fadd_rn(pd, RP[(size_t)i * 784 + j]); // + rp
            if (i == j) v = __fadd_rn(v, 100000.0f);           // diag add INF
            dist[(size_t)(cls * 784 + i) * 784 + j] = v;
        }
    }
}

// ---- per-row exact top-10 (jax tie-break: lower index first) ----------------
__global__ __launch_bounds__(256) void topk_kernel(const float* __restrict__ dist,
                                                   int* __restrict__ out, int b) {
    int cls = blockIdx.y, i = blockIdx.x;
    const float* row = dist + (size_t)(cls * 784 + i) * 784;
    __shared__ unsigned long long keys[784];
    __shared__ unsigned long long wmin[4];
    int t = threadIdx.x;
    for (int j = t; j < 784; j += 256) {
        float v = row[j];
        unsigned u = __float_as_uint(v);
        u = (u & 0x80000000u) ? ~u : (u | 0x80000000u);   // order-preserving map
        keys[j] = ((unsigned long long)u << 32) | (unsigned long long)j;
    }
    __syncthreads();
    int oh = cls >> 1, ow = cls & 1;
    int gi = b * N_NODES + (oh + 2 * (i / 28)) * 56 + (ow + 2 * (i % 28));
    for (int k = 0; k < 10; ++k) {
        unsigned long long m = 0xFFFFFFFFFFFFFFFFull;
        for (int j = t; j < 784; j += 256) {
            unsigned long long v = keys[j];
            m = (v < m) ? v : m;
        }
        #pragma unroll
        for (int off = 32; off > 0; off >>= 1) {
            unsigned long long o = __shfl_down(m, off);
            m = (o < m) ? o : m;
        }
        if ((t & 63) == 0) wmin[t >> 6] = m;
        __syncthreads();
        if (t == 0) {
            unsigned long long best = wmin[0];
            #pragma unroll
            for (int w = 1; w < 4; ++w) best = (wmin[w] < best) ? wmin[w] : best;
            int j = (int)(best & 0xFFFFFFFFull);
            keys[j] = 0xFFFFFFFFFFFFFFFFull;              // remove winner
            int gj = b * N_NODES + (oh + 2 * (j / 28)) * 56 + (ow + 2 * (j % 28));
            size_t e = ((size_t)gi * 10 + k) * 2;
            out[e] = gj;       // neighbor (already batch-offset)
            out[e + 1] = gi;   // source
        }
        __syncthreads();
    }
}

extern "C" void kernel_launch(void* const* d_in, const int* in_sizes, int n_in,
                              void* d_out, int out_size, void* d_ws, size_t ws_size,
                              hipStream_t stream) {
    const float* x = (const float*)d_in[0];
    int* out = (int*)d_out;
    char* base = (char*)d_ws;
    float* norms = (float*)(base);
    float* sq    = (float*)(base + 100352);
    float* pe    = (float*)(base + 200704);
    float* RP    = (float*)(base + 1404928);
    float* dist  = (float*)(base + 3863552);

    pe_kernel<<<dim3(784), dim3(96), 0, stream>>>(pe);
    norm_sq_kernel<<<dim3(784), dim3(256), 0, stream>>>(x, norms, sq);
    rp_gemm<<<dim3(13, 13), dim3(256), 0, stream>>>(pe, RP);
    for (int b = 0; b < NB; ++b) {
        dist_gemm<<<dim3(13, 13, 4), dim3(256), 0, stream>>>(x, norms, sq, RP, dist, b);
        topk_kernel<<<dim3(784, 4), dim3(256), 0, stream>>>(dist, out, b);
    }
}

// Round 10
// 567.504 us; speedup vs baseline: 1.3233x; 1.3233x over previous
//
#include <hip/hip_runtime.h>
#include <hip/hip_bf16.h>

#define N_NODES 3136
#define NB 8
#define DIMF 384

// ws layout (bytes):
//   norms : float[25088]   @ 0        (100352)
//   sq    : float[25088]   @ 100352   (100352)
//   pe    : float[301056]  @ 200704   (1204224)   784 x 384
//   RP    : float[614656]  @ 1404928  (2458624)   784 x 784
//   dist  : float[2458624] @ 3863552  (9834496)   4 x 784 x 784 per-batch reuse
// total 13,698,048 B
//
// NOTE: dist arithmetic (np.einsum 4-lane SIMD replica + hadd tree + f32
// chains) is load-bearing for correctness (rounds 3-9). Do not touch the
// per-output operation order; only scheduling/thread-mapping may change.

// ---- pe table: replica of numpy f32 _sincos_1d ------------------------------
__global__ void pe_kernel(float* __restrict__ pe) {
    int p = blockIdx.x;          // 0..783, p = r*28 + c, positions (2r, 2c)
    int d = threadIdx.x;         // 0..95
    int r = p / 28, c = p % 28;
    float wpos = (float)(2 * c);     // emb_h uses grid[0] = W coords
    float hpos = (float)(2 * r);
    float wexp = (float)d / 96.0f;                    // f32 divide, as np
    float t = (float)pow(10000.0, (double)wexp);      // cr-f32 of 10000**w
    float om = 1.0f / t;                              // f32 divide, as np
    float aw = wpos * om;                             // f32 product (einsum)
    float ah = hpos * om;
    pe[(size_t)p * DIMF + d]       = (float)sin((double)aw);  // cr-f32 sin(f32 arg)
    pe[(size_t)p * DIMF + 96 + d]  = (float)cos((double)aw);
    pe[(size_t)p * DIMF + 192 + d] = (float)sin((double)ah);
    pe[(size_t)p * DIMF + 288 + d] = (float)cos((double)ah);
}

// ---- norm & sq: numpy pairwise-sum replica (384=(96+96)+(96+96), 8-acc base) -
__global__ __launch_bounds__(256) void norm_sq_kernel(const float* __restrict__ x,
                                                      float* __restrict__ norms,
                                                      float* __restrict__ sq) {
    int tid = threadIdx.x;
    int g = blockIdx.x * 32 + (tid >> 3);     // node 0..25087
    int lane = tid & 7;
    const float* row = x + (size_t)g * DIMF;
    float p4[4];
    #pragma unroll
    for (int b = 0; b < 4; ++b) {
        const float* blk = row + 96 * b;
        float t0 = blk[lane];
        float r = __fmul_rn(t0, t0);
        for (int i = 8; i < 96; i += 8) {
            float t = blk[i + lane];
            r = __fadd_rn(r, __fmul_rn(t, t));
        }
        r = __fadd_rn(r, __shfl_xor(r, 1));   // (r0+r1) etc.
        r = __fadd_rn(r, __shfl_xor(r, 2));   // ((r0+r1)+(r2+r3)) etc.
        r = __fadd_rn(r, __shfl_xor(r, 4));   // full 8-acc combine
        p4[b] = r;
    }
    float s = __fadd_rn(__fadd_rn(p4[0], p4[1]), __fadd_rn(p4[2], p4[3]));
    float n = fmaxf(__fsqrt_rn(s), 1e-12f);   // np: sqrt f32, clip
    #pragma unroll
    for (int b = 0; b < 4; ++b) {
        const float* blk = row + 96 * b;
        float t0 = __fdiv_rn(blk[lane], n);   // f32 divide, as np broadcast
        float r = __fmul_rn(t0, t0);
        for (int i = 8; i < 96; i += 8) {
            float t = __fdiv_rn(blk[i + lane], n);
            r = __fadd_rn(r, __fmul_rn(t, t));
        }
        r = __fadd_rn(r, __shfl_xor(r, 1));
        r = __fadd_rn(r, __shfl_xor(r, 2));
        r = __fadd_rn(r, __shfl_xor(r, 4));
        p4[b] = r;
    }
    float s2 = __fadd_rn(__fadd_rn(p4[0], p4[1]), __fadd_rn(p4[2], p4[3]));
    if (lane == 0) {
        int b = g / N_NODES, loc = g % N_NODES;
        int r = loc / 56, c = loc % 56;
        int cls = (r & 1) * 2 + (c & 1);
        int m = (r >> 1) * 28 + (c >> 1);
        norms[g] = n;
        sq[(size_t)(b * 4 + cls) * 784 + m] = s2;
    }
}

// ---- RP: OpenBLAS-sgemm replica (sequential-k f32 FMA) + ref's f32 chain ----
// 512 threads, 64x64 tile, 8 outputs/thread (2 row-frags x 4 col-frags)
__global__ __launch_bounds__(512, 4) void rp_gemm(const float* __restrict__ pe,
                                                  float* __restrict__ RP) {
    int brow = blockIdx.y * 64, bcol = blockIdx.x * 64;
    __shared__ float As[64][36], Bs[64][36];
    int t = threadIdx.x;                 // 0..511
    int tx = t & 15, ty = t >> 4;        // tx 0..15, ty 0..31
    float acc[2][4] = {{0.f}};
    for (int k0 = 0; k0 < DIMF; k0 += 32) {
        __syncthreads();
        {
            int m = t >> 3, kq = t & 7;  // 512 = 64 rows x 8 quads
            float4 v = make_float4(0.f, 0.f, 0.f, 0.f);
            int rowi = brow + m;
            if (rowi < 784) v = *(const float4*)(pe + (size_t)rowi * DIMF + k0 + kq * 4);
            *(float4*)&As[m][kq * 4] = v;
            float4 w = make_float4(0.f, 0.f, 0.f, 0.f);
            int coli = bcol + m;
            if (coli < 784) w = *(const float4*)(pe + (size_t)coli * DIMF + k0 + kq * 4);
            *(float4*)&Bs[m][kq * 4] = w;
        }
        __syncthreads();
        #pragma unroll 4
        for (int k = 0; k < 32; ++k) {          // ascending k, single FMA chain
            float ra[2], rb[4];
            #pragma unroll
            for (int ii = 0; ii < 2; ++ii) ra[ii] = As[ty + 32 * ii][k];
            #pragma unroll
            for (int jj = 0; jj < 4; ++jj) rb[jj] = Bs[tx + 16 * jj][k];
            #pragma unroll
            for (int ii = 0; ii < 2; ++ii)
                #pragma unroll
                for (int jj = 0; jj < 4; ++jj)
                    acc[ii][jj] = __fmaf_rn(ra[ii], rb[jj], acc[ii][jj]);
        }
    }
    #pragma unroll
    for (int ii = 0; ii < 2; ++ii) {
        int i = brow + ty + 32 * ii;
        if (i >= 784) continue;
        #pragma unroll
        for (int jj = 0; jj < 4; ++jj) {
            int j = bcol + tx + 16 * jj;
            if (j >= 784) continue;
            float X = acc[ii][jj];
            float num = __fmul_rn(2.0f, X);         // np: 2.0 * M
            float q = __fdiv_rn(num, 384.0f);       // np: / DIM
            RP[(size_t)i * 784 + j] = -q;           // np: unary negate
        }
    }
}

// ---- dist: np.einsum replica — 4-lane SSE mul+add partials, hadd tree -------
// 512 threads, 64x64 tile, 8 outputs/thread; per-output arithmetic identical
__global__ __launch_bounds__(512, 4) void dist_gemm(const float* __restrict__ x,
                                                    const float* __restrict__ norms,
                                                    const float* __restrict__ sq,
                                                    const float* __restrict__ RP,
                                                    float* __restrict__ dist, int b) {
    int cls = blockIdx.z;
    int brow = blockIdx.y * 64, bcol = blockIdx.x * 64;
    int oh = cls >> 1, ow = cls & 1;
    __shared__ float As[64][36], Bs[64][36];
    int t = threadIdx.x;                 // 0..511
    int tx = t & 15, ty = t >> 4;        // tx 0..15, ty 0..31
    float4 acc[2][4];
    #pragma unroll
    for (int ii = 0; ii < 2; ++ii)
        #pragma unroll
        for (int jj = 0; jj < 4; ++jj) acc[ii][jj] = make_float4(0.f, 0.f, 0.f, 0.f);
    for (int k0 = 0; k0 < DIMF; k0 += 32) {
        __syncthreads();
        {
            int m = t >> 3, kq = t & 7;  // one float4 per array per thread
            {
                int rowi = brow + m;
                float4 v = make_float4(0.f, 0.f, 0.f, 0.f);
                if (rowi < 784) {
                    int g = b * N_NODES + (oh + 2 * (rowi / 28)) * 56 + (ow + 2 * (rowi % 28));
                    float4 a = *(const float4*)(x + (size_t)g * DIMF + k0 + kq * 4);
                    float n = norms[g];
                    v.x = __fdiv_rn(a.x, n); v.y = __fdiv_rn(a.y, n);
                    v.z = __fdiv_rn(a.z, n); v.w = __fdiv_rn(a.w, n);   // = np xn bits
                }
                *(float4*)&As[m][kq * 4] = v;
            }
            {
                int coli = bcol + m;
                float4 v = make_float4(0.f, 0.f, 0.f, 0.f);
                if (coli < 784) {
                    int g = b * N_NODES + (oh + 2 * (coli / 28)) * 56 + (ow + 2 * (coli % 28));
                    float4 a = *(const float4*)(x + (size_t)g * DIMF + k0 + kq * 4);
                    float n = norms[g];
                    v.x = __fdiv_rn(a.x, n); v.y = __fdiv_rn(a.y, n);
                    v.z = __fdiv_rn(a.z, n); v.w = __fdiv_rn(a.w, n);
                }
                *(float4*)&Bs[m][kq * 4] = v;
            }
        }
        __syncthreads();
        // np.einsum f32 contig SIMD: lane l accumulates k = 4i+l, mul then add
        #pragma unroll 2
        for (int k4 = 0; k4 < 32; k4 += 4) {
            float4 ra[2], rb[4];
            #pragma unroll
            for (int ii = 0; ii < 2; ++ii) ra[ii] = *(float4*)&As[ty + 32 * ii][k4];
            #pragma unroll
            for (int jj = 0; jj < 4; ++jj) rb[jj] = *(float4*)&Bs[tx + 16 * jj][k4];
            #pragma unroll
            for (int ii = 0; ii < 2; ++ii)
                #pragma unroll
                for (int jj = 0; jj < 4; ++jj) {
                    acc[ii][jj].x = __fadd_rn(acc[ii][jj].x, __fmul_rn(ra[ii].x, rb[jj].x));
                    acc[ii][jj].y = __fadd_rn(acc[ii][jj].y, __fmul_rn(ra[ii].y, rb[jj].y));
                    acc[ii][jj].z = __fadd_rn(acc[ii][jj].z, __fmul_rn(ra[ii].z, rb[jj].z));
                    acc[ii][jj].w = __fadd_rn(acc[ii][jj].w, __fmul_rn(ra[ii].w, rb[jj].w));
                }
        }
    }
    int sqb = (b * 4 + cls) * 784;
    #pragma unroll
    for (int ii = 0; ii < 2; ++ii) {
        int i = brow + ty + 32 * ii;
        if (i >= 784) continue;
        float sqi = sq[sqb + i];
        #pragma unroll
        for (int jj = 0; jj < 4; ++jj) {
            int j = bcol + tx + 16 * jj;
            if (j >= 784) continue;
            float4 a = acc[ii][jj];
            // SSE3 hadd tree: (p0+p1) + (p2+p3)
            float X  = __fadd_rn(__fadd_rn(a.x, a.y), __fadd_rn(a.z, a.w));
            float t1 = __fadd_rn(sqi, sq[sqb + j]);            // sq_i + sq_j
            float pd = __fsub_rn(t1, __fmul_rn(2.0f, X));      // - 2*dot
            float v  = __fadd_rn(pd, RP[(size_t)i * 784 + j]); // + rp
            if (i == j) v = __fadd_rn(v, 100000.0f);           // diag add INF
            dist[(size_t)(cls * 784 + i) * 784 + j] = v;
        }
    }
}

// ---- per-row exact top-10, wave-per-row (no LDS, no barriers) ---------------
// u64 keys (mapped f32 | idx) keep jax tie-break: lower index first.
__global__ __launch_bounds__(256) void topk_kernel(const float* __restrict__ dist,
                                                   int* __restrict__ out, int b) {
    int cls = blockIdx.y;
    int i = blockIdx.x * 4 + (threadIdx.x >> 6);   // row 0..783
    int lane = threadIdx.x & 63;
    const float* row = dist + (size_t)(cls * 784 + i) * 784;
    unsigned long long k[10];
    #pragma unroll
    for (int q = 0; q < 10; ++q) k[q] = 0xFFFFFFFFFFFFFFFFull;
    #pragma unroll
    for (int it = 0; it < 13; ++it) {
        int j = lane + it * 64;
        if (j < 784) {
            float v = row[j];
            unsigned u = __float_as_uint(v);
            u = (u & 0x80000000u) ? ~u : (u | 0x80000000u);   // order-preserving map
            unsigned long long key = ((unsigned long long)u << 32) | (unsigned)j;
            if (key < k[9]) {
                k[9] = key;                                  // insert + bubble up
                #pragma unroll
                for (int q = 9; q >= 1; --q) {
                    unsigned long long a = k[q - 1], c = k[q];
                    bool sw = (c < a);
                    k[q - 1] = sw ? c : a;
                    k[q]     = sw ? a : c;
                }
            }
        }
    }
    int oh = cls >> 1, ow = cls & 1;
    int gi = b * N_NODES + (oh + 2 * (i / 28)) * 56 + (ow + 2 * (i % 28));
    #pragma unroll
    for (int kk = 0; kk < 10; ++kk) {
        unsigned long long m = k[0];
        #pragma unroll
        for (int off = 32; off > 0; off >>= 1) {
            unsigned long long o = __shfl_xor(m, off);       // all lanes get min
            m = (o < m) ? o : m;
        }
        bool win = (k[0] == m);                              // unique (idx in key)
        #pragma unroll
        for (int q = 0; q < 9; ++q) k[q] = win ? k[q + 1] : k[q];
        k[9] = win ? 0xFFFFFFFFFFFFFFFFull : k[9];
        if (lane == 0) {
            int j = (int)(m & 0xFFFFFFFFull);
            int gj = b * N_NODES + (oh + 2 * (j / 28)) * 56 + (ow + 2 * (j % 28));
            size_t e = ((size_t)gi * 10 + kk) * 2;
            out[e] = gj;       // neighbor (already batch-offset)
            out[e + 1] = gi;   // source
        }
    }
}

extern "C" void kernel_launch(void* const* d_in, const int* in_sizes, int n_in,
                              void* d_out, int out_size, void* d_ws, size_t ws_size,
                              hipStream_t stream) {
    const float* x = (const float*)d_in[0];
    int* out = (int*)d_out;
    char* base = (char*)d_ws;
    float* norms = (float*)(base);
    float* sq    = (float*)(base + 100352);
    float* pe    = (float*)(base + 200704);
    float* RP    = (float*)(base + 1404928);
    float* dist  = (float*)(base + 3863552);

    pe_kernel<<<dim3(784), dim3(96), 0, stream>>>(pe);
    norm_sq_kernel<<<dim3(784), dim3(256), 0, stream>>>(x, norms, sq);
    rp_gemm<<<dim3(13, 13), dim3(512), 0, stream>>>(pe, RP);
    for (int b = 0; b < NB; ++b) {
        dist_gemm<<<dim3(13, 13, 4), dim3(512), 0, stream>>>(x, norms, sq, RP, dist, b);
        topk_kernel<<<dim3(196, 4), dim3(256), 0, stream>>>(dist, out, b);
    }
}

// Round 12
// 452.952 us; speedup vs baseline: 1.6579x; 1.2529x over previous
//
#include <hip/hip_runtime.h>
#include <hip/hip_bf16.h>

#define N_NODES 3136
#define NB 8
#define DIMF 384

// ws layout (bytes):
//   norms : float[25088]   @ 0        (100352)
//   sq    : float[25088]   @ 100352   (100352)
//   pe    : float[301056]  @ 200704   (1204224)   784 x 384
//   RP    : float[614656]  @ 1404928  (2458624)   784 x 784
//   dist  : @ 3863552, nbatch * 4 * 784 * 784 floats (9834496 B per batch-slab)
//           nbatch chosen at runtime from ws_size (>=1 guaranteed; 8 => 82.5 MB)
//
// NOTE: dist arithmetic (np.einsum 4-lane SIMD replica + hadd tree + f32
// chains) is load-bearing for correctness (rounds 3-9). Do not touch the
// per-output operation order; only scheduling/thread-mapping may change.

// ---- pe table: replica of numpy f32 _sincos_1d ------------------------------
__global__ void pe_kernel(float* __restrict__ pe) {
    int p = blockIdx.x;          // 0..783, p = r*28 + c, positions (2r, 2c)
    int d = threadIdx.x;         // 0..95
    int r = p / 28, c = p % 28;
    float wpos = (float)(2 * c);     // emb_h uses grid[0] = W coords
    float hpos = (float)(2 * r);
    float wexp = (float)d / 96.0f;                    // f32 divide, as np
    float t = (float)pow(10000.0, (double)wexp);      // cr-f32 of 10000**w
    float om = 1.0f / t;                              // f32 divide, as np
    float aw = wpos * om;                             // f32 product (einsum)
    float ah = hpos * om;
    pe[(size_t)p * DIMF + d]       = (float)sin((double)aw);  // cr-f32 sin(f32 arg)
    pe[(size_t)p * DIMF + 96 + d]  = (float)cos((double)aw);
    pe[(size_t)p * DIMF + 192 + d] = (float)sin((double)ah);
    pe[(size_t)p * DIMF + 288 + d] = (float)cos((double)ah);
}

// ---- norm & sq: numpy pairwise-sum replica (384=(96+96)+(96+96), 8-acc base) -
__global__ __launch_bounds__(256) void norm_sq_kernel(const float* __restrict__ x,
                                                      float* __restrict__ norms,
                                                      float* __restrict__ sq) {
    int tid = threadIdx.x;
    int g = blockIdx.x * 32 + (tid >> 3);     // node 0..25087
    int lane = tid & 7;
    const float* row = x + (size_t)g * DIMF;
    float p4[4];
    #pragma unroll
    for (int b = 0; b < 4; ++b) {
        const float* blk = row + 96 * b;
        float t0 = blk[lane];
        float r = __fmul_rn(t0, t0);
        for (int i = 8; i < 96; i += 8) {
            float t = blk[i + lane];
            r = __fadd_rn(r, __fmul_rn(t, t));
        }
        r = __fadd_rn(r, __shfl_xor(r, 1));   // (r0+r1) etc.
        r = __fadd_rn(r, __shfl_xor(r, 2));   // ((r0+r1)+(r2+r3)) etc.
        r = __fadd_rn(r, __shfl_xor(r, 4));   // full 8-acc combine
        p4[b] = r;
    }
    float s = __fadd_rn(__fadd_rn(p4[0], p4[1]), __fadd_rn(p4[2], p4[3]));
    float n = fmaxf(__fsqrt_rn(s), 1e-12f);   // np: sqrt f32, clip
    #pragma unroll
    for (int b = 0; b < 4; ++b) {
        const float* blk = row + 96 * b;
        float t0 = __fdiv_rn(blk[lane], n);   // f32 divide, as np broadcast
        float r = __fmul_rn(t0, t0);
        for (int i = 8; i < 96; i += 8) {
            float t = __fdiv_rn(blk[i + lane], n);
            r = __fadd_rn(r, __fmul_rn(t, t));
        }
        r = __fadd_rn(r, __shfl_xor(r, 1));
        r = __fadd_rn(r, __shfl_xor(r, 2));
        r = __fadd_rn(r, __shfl_xor(r, 4));
        p4[b] = r;
    }
    float s2 = __fadd_rn(__fadd_rn(p4[0], p4[1]), __fadd_rn(p4[2], p4[3]));
    if (lane == 0) {
        int b = g / N_NODES, loc = g % N_NODES;
        int r = loc / 56, c = loc % 56;
        int cls = (r & 1) * 2 + (c & 1);
        int m = (r >> 1) * 28 + (c >> 1);
        norms[g] = n;
        sq[(size_t)(b * 4 + cls) * 784 + m] = s2;
    }
}

// ---- RP: OpenBLAS-sgemm replica (sequential-k f32 FMA) + ref's f32 chain ----
__global__ __launch_bounds__(512, 4) void rp_gemm(const float* __restrict__ pe,
                                                  float* __restrict__ RP) {
    int brow = blockIdx.y * 64, bcol = blockIdx.x * 64;
    __shared__ float As[64][36], Bs[64][36];
    int t = threadIdx.x;                 // 0..511
    int tx = t & 15, ty = t >> 4;        // tx 0..15, ty 0..31
    float acc[2][4] = {{0.f}};
    for (int k0 = 0; k0 < DIMF; k0 += 32) {
        __syncthreads();
        {
            int m = t >> 3, kq = t & 7;  // 512 = 64 rows x 8 quads
            float4 v = make_float4(0.f, 0.f, 0.f, 0.f);
            int rowi = brow + m;
            if (rowi < 784) v = *(const float4*)(pe + (size_t)rowi * DIMF + k0 + kq * 4);
            *(float4*)&As[m][kq * 4] = v;
            float4 w = make_float4(0.f, 0.f, 0.f, 0.f);
            int coli = bcol + m;
            if (coli < 784) w = *(const float4*)(pe + (size_t)coli * DIMF + k0 + kq * 4);
            *(float4*)&Bs[m][kq * 4] = w;
        }
        __syncthreads();
        #pragma unroll 4
        for (int k = 0; k < 32; ++k) {          // ascending k, single FMA chain
            float ra[2], rb[4];
            #pragma unroll
            for (int ii = 0; ii < 2; ++ii) ra[ii] = As[ty + 32 * ii][k];
            #pragma unroll
            for (int jj = 0; jj < 4; ++jj) rb[jj] = Bs[tx + 16 * jj][k];
            #pragma unroll
            for (int ii = 0; ii < 2; ++ii)
                #pragma unroll
                for (int jj = 0; jj < 4; ++jj)
                    acc[ii][jj] = __fmaf_rn(ra[ii], rb[jj], acc[ii][jj]);
        }
    }
    #pragma unroll
    for (int ii = 0; ii < 2; ++ii) {
        int i = brow + ty + 32 * ii;
        if (i >= 784) continue;
        #pragma unroll
        for (int jj = 0; jj < 4; ++jj) {
            int j = bcol + tx + 16 * jj;
            if (j >= 784) continue;
            float X = acc[ii][jj];
            float num = __fmul_rn(2.0f, X);         // np: 2.0 * M
            float q = __fdiv_rn(num, 384.0f);       // np: / DIM
            RP[(size_t)i * 784 + j] = -q;           // np: unary negate
        }
    }
}

// ---- dist: np.einsum replica — 4-lane SSE mul+add partials, hadd tree -------
// z = plane index: b = bo + z/4, cls = z%4; plane z of dist slab.
__global__ __launch_bounds__(512, 4) void dist_gemm(const float* __restrict__ x,
                                                    const float* __restrict__ norms,
                                                    const float* __restrict__ sq,
                                                    const float* __restrict__ RP,
                                                    float* __restrict__ dist, int bo) {
    int z = blockIdx.z;
    int b = bo + (z >> 2), cls = z & 3;
    int brow = blockIdx.y * 64, bcol = blockIdx.x * 64;
    int oh = cls >> 1, ow = cls & 1;
    __shared__ float As[64][36], Bs[64][36];
    int t = threadIdx.x;                 // 0..511
    int tx = t & 15, ty = t >> 4;        // tx 0..15, ty 0..31
    float4 acc[2][4];
    #pragma unroll
    for (int ii = 0; ii < 2; ++ii)
        #pragma unroll
        for (int jj = 0; jj < 4; ++jj) acc[ii][jj] = make_float4(0.f, 0.f, 0.f, 0.f);
    for (int k0 = 0; k0 < DIMF; k0 += 32) {
        __syncthreads();
        {
            int m = t >> 3, kq = t & 7;  // one float4 per array per thread
            {
                int rowi = brow + m;
                float4 v = make_float4(0.f, 0.f, 0.f, 0.f);
                if (rowi < 784) {
                    int g = b * N_NODES + (oh + 2 * (rowi / 28)) * 56 + (ow + 2 * (rowi % 28));
                    float4 a = *(const float4*)(x + (size_t)g * DIMF + k0 + kq * 4);
                    float n = norms[g];
                    v.x = __fdiv_rn(a.x, n); v.y = __fdiv_rn(a.y, n);
                    v.z = __fdiv_rn(a.z, n); v.w = __fdiv_rn(a.w, n);   // = np xn bits
                }
                *(float4*)&As[m][kq * 4] = v;
            }
            {
                int coli = bcol + m;
                float4 v = make_float4(0.f, 0.f, 0.f, 0.f);
                if (coli < 784) {
                    int g = b * N_NODES + (oh + 2 * (coli / 28)) * 56 + (ow + 2 * (coli % 28));
                    float4 a = *(const float4*)(x + (size_t)g * DIMF + k0 + kq * 4);
                    float n = norms[g];
                    v.x = __fdiv_rn(a.x, n); v.y = __fdiv_rn(a.y, n);
                    v.z = __fdiv_rn(a.z, n); v.w = __fdiv_rn(a.w, n);
                }
                *(float4*)&Bs[m][kq * 4] = v;
            }
        }
        __syncthreads();
        // np.einsum f32 contig SIMD: lane l accumulates k = 4i+l, mul then add
        #pragma unroll 2
        for (int k4 = 0; k4 < 32; k4 += 4) {
            float4 ra[2], rb[4];
            #pragma unroll
            for (int ii = 0; ii < 2; ++ii) ra[ii] = *(float4*)&As[ty + 32 * ii][k4];
            #pragma unroll
            for (int jj = 0; jj < 4; ++jj) rb[jj] = *(float4*)&Bs[tx + 16 * jj][k4];
            #pragma unroll
            for (int ii = 0; ii < 2; ++ii)
                #pragma unroll
                for (int jj = 0; jj < 4; ++jj) {
                    acc[ii][jj].x = __fadd_rn(acc[ii][jj].x, __fmul_rn(ra[ii].x, rb[jj].x));
                    acc[ii][jj].y = __fadd_rn(acc[ii][jj].y, __fmul_rn(ra[ii].y, rb[jj].y));
                    acc[ii][jj].z = __fadd_rn(acc[ii][jj].z, __fmul_rn(ra[ii].z, rb[jj].z));
                    acc[ii][jj].w = __fadd_rn(acc[ii][jj].w, __fmul_rn(ra[ii].w, rb[jj].w));
                }
        }
    }
    int sqb = (b * 4 + cls) * 784;
    float* plane = dist + (size_t)z * 784 * 784;
    #pragma unroll
    for (int ii = 0; ii < 2; ++ii) {
        int i = brow + ty + 32 * ii;
        if (i >= 784) continue;
        float sqi = sq[sqb + i];
        #pragma unroll
        for (int jj = 0; jj < 4; ++jj) {
            int j = bcol + tx + 16 * jj;
            if (j >= 784) continue;
            float4 a = acc[ii][jj];
            // SSE3 hadd tree: (p0+p1) + (p2+p3)
            float X  = __fadd_rn(__fadd_rn(a.x, a.y), __fadd_rn(a.z, a.w));
            float t1 = __fadd_rn(sqi, sq[sqb + j]);            // sq_i + sq_j
            float pd = __fsub_rn(t1, __fmul_rn(2.0f, X));      // - 2*dot
            float v  = __fadd_rn(pd, RP[(size_t)i * 784 + j]); // + rp
            if (i == j) v = __fadd_rn(v, 100000.0f);           // diag add INF
            plane[(size_t)i * 784 + j] = v;
        }
    }
}

// ---- per-row exact top-10, wave-per-row (no LDS, no barriers) ---------------
// u64 keys (mapped f32 | idx) keep jax tie-break: lower index first.
// y = plane index: b = bo + y/4, cls = y%4.
__global__ __launch_bounds__(256) void topk_kernel(const float* __restrict__ dist,
                                                   int* __restrict__ out, int bo) {
    int y = blockIdx.y;
    int b = bo + (y >> 2), cls = y & 3;
    int i = blockIdx.x * 4 + (threadIdx.x >> 6);   // row 0..783
    int lane = threadIdx.x & 63;
    const float* row = dist + (size_t)y * 784 * 784 + (size_t)i * 784;
    unsigned long long k[10];
    #pragma unroll
    for (int q = 0; q < 10; ++q) k[q] = 0xFFFFFFFFFFFFFFFFull;
    #pragma unroll
    for (int it = 0; it < 13; ++it) {
        int j = lane + it * 64;
        if (j < 784) {
            float v = row[j];
            unsigned u = __float_as_uint(v);
            u = (u & 0x80000000u) ? ~u : (u | 0x80000000u);   // order-preserving map
            unsigned long long key = ((unsigned long long)u << 32) | (unsigned)j;
            if (key < k[9]) {
                k[9] = key;                                  // insert + bubble up
                #pragma unroll
                for (int q = 9; q >= 1; --q) {
                    unsigned long long a = k[q - 1], c = k[q];
                    bool sw = (c < a);
                    k[q - 1] = sw ? c : a;
                    k[q]     = sw ? a : c;
                }
            }
        }
    }
    int oh = cls >> 1, ow = cls & 1;
    int gi = b * N_NODES + (oh + 2 * (i / 28)) * 56 + (ow + 2 * (i % 28));
    #pragma unroll
    for (int kk = 0; kk < 10; ++kk) {
        unsigned long long m = k[0];
        #pragma unroll
        for (int off = 32; off > 0; off >>= 1) {
            unsigned long long o = __shfl_xor(m, off);       // all lanes get min
            m = (o < m) ? o : m;
        }
        bool win = (k[0] == m);                              // unique (idx in key)
        #pragma unroll
        for (int q = 0; q < 9; ++q) k[q] = win ? k[q + 1] : k[q];
        k[9] = win ? 0xFFFFFFFFFFFFFFFFull : k[9];
        if (lane == 0) {
            int j = (int)(m & 0xFFFFFFFFull);
            int gj = b * N_NODES + (oh + 2 * (j / 28)) * 56 + (ow + 2 * (j % 28));
            size_t e = ((size_t)gi * 10 + kk) * 2;
            out[e] = gj;       // neighbor (already batch-offset)
            out[e + 1] = gi;   // source
        }
    }
}

extern "C" void kernel_launch(void* const* d_in, const int* in_sizes, int n_in,
                              void* d_out, int out_size, void* d_ws, size_t ws_size,
                              hipStream_t stream) {
    const float* x = (const float*)d_in[0];
    int* out = (int*)d_out;
    char* base = (char*)d_ws;
    float* norms = (float*)(base);
    float* sq    = (float*)(base + 100352);
    float* pe    = (float*)(base + 200704);
    float* RP    = (float*)(base + 1404928);
    float* dist  = (float*)(base + 3863552);

    // batch as many b-iterations as the workspace can hold dist slabs for
    const size_t fixed = 3863552, slab = 9834496;
    size_t avail = (ws_size > fixed) ? (ws_size - fixed) : slab;
    int fit = (int)(avail / slab);
    int nbatch = (fit >= 8) ? 8 : (fit >= 4) ? 4 : (fit >= 2) ? 2 : 1;

    pe_kernel<<<dim3(784), dim3(96), 0, stream>>>(pe);
    norm_sq_kernel<<<dim3(784), dim3(256), 0, stream>>>(x, norms, sq);
    rp_gemm<<<dim3(13, 13), dim3(512), 0, stream>>>(pe, RP);
    for (int bo = 0; bo < NB; bo += nbatch) {
        dist_gemm<<<dim3(13, 13, 4 * nbatch), dim3(512), 0, stream>>>(x, norms, sq, RP, dist, bo);
        topk_kernel<<<dim3(196, 4 * nbatch), dim3(256), 0, stream>>>(dist, out, bo);
    }
}

// Round 13
// 322.048 us; speedup vs baseline: 2.3319x; 1.4065x over previous
//
#include <hip/hip_runtime.h>
#include <hip/hip_bf16.h>

#define N_NODES 3136
#define NB 8
#define DIMF 384

// ws layout (bytes):
//   norms : float[25088]   @ 0        (100352)
//   sq    : float[25088]   @ 100352   (100352)
//   pe    : float[301056]  @ 200704   (1204224)   784 x 384
//   RP    : float[614656]  @ 1404928  (2458624)   784 x 784
//   dist  : @ 3863552, nbatch * 4 * 784 * 784 floats (9834496 B per batch-slab)
//
// NOTE: dist arithmetic (np.einsum 4-lane SIMD replica + hadd tree + f32
// chains) is load-bearing for correctness (rounds 3-9). Do not touch the
// per-output operation order; only scheduling/thread-mapping may change.
// Symmetry: dist plane is bitwise symmetric (commutative mul/fadd, k-phase
// depends on k only, RP bitwise symmetric) -> compute upper-triangle tiles
// and mirror-store (round 12->13 change).

// ---- pe table: replica of numpy f32 _sincos_1d ------------------------------
__global__ void pe_kernel(float* __restrict__ pe) {
    int p = blockIdx.x;          // 0..783, p = r*28 + c, positions (2r, 2c)
    int d = threadIdx.x;         // 0..95
    int r = p / 28, c = p % 28;
    float wpos = (float)(2 * c);     // emb_h uses grid[0] = W coords
    float hpos = (float)(2 * r);
    float wexp = (float)d / 96.0f;                    // f32 divide, as np
    float t = (float)pow(10000.0, (double)wexp);      // cr-f32 of 10000**w
    float om = 1.0f / t;                              // f32 divide, as np
    float aw = wpos * om;                             // f32 product (einsum)
    float ah = hpos * om;
    pe[(size_t)p * DIMF + d]       = (float)sin((double)aw);  // cr-f32 sin(f32 arg)
    pe[(size_t)p * DIMF + 96 + d]  = (float)cos((double)aw);
    pe[(size_t)p * DIMF + 192 + d] = (float)sin((double)ah);
    pe[(size_t)p * DIMF + 288 + d] = (float)cos((double)ah);
}

// ---- norm & sq: numpy pairwise-sum replica (384=(96+96)+(96+96), 8-acc base) -
__global__ __launch_bounds__(256) void norm_sq_kernel(const float* __restrict__ x,
                                                      float* __restrict__ norms,
                                                      float* __restrict__ sq) {
    int tid = threadIdx.x;
    int g = blockIdx.x * 32 + (tid >> 3);     // node 0..25087
    int lane = tid & 7;
    const float* row = x + (size_t)g * DIMF;
    float p4[4];
    #pragma unroll
    for (int b = 0; b < 4; ++b) {
        const float* blk = row + 96 * b;
        float t0 = blk[lane];
        float r = __fmul_rn(t0, t0);
        for (int i = 8; i < 96; i += 8) {
            float t = blk[i + lane];
            r = __fadd_rn(r, __fmul_rn(t, t));
        }
        r = __fadd_rn(r, __shfl_xor(r, 1));   // (r0+r1) etc.
        r = __fadd_rn(r, __shfl_xor(r, 2));   // ((r0+r1)+(r2+r3)) etc.
        r = __fadd_rn(r, __shfl_xor(r, 4));   // full 8-acc combine
        p4[b] = r;
    }
    float s = __fadd_rn(__fadd_rn(p4[0], p4[1]), __fadd_rn(p4[2], p4[3]));
    float n = fmaxf(__fsqrt_rn(s), 1e-12f);   // np: sqrt f32, clip
    #pragma unroll
    for (int b = 0; b < 4; ++b) {
        const float* blk = row + 96 * b;
        float t0 = __fdiv_rn(blk[lane], n);   // f32 divide, as np broadcast
        float r = __fmul_rn(t0, t0);
        for (int i = 8; i < 96; i += 8) {
            float t = __fdiv_rn(blk[i + lane], n);
            r = __fadd_rn(r, __fmul_rn(t, t));
        }
        r = __fadd_rn(r, __shfl_xor(r, 1));
        r = __fadd_rn(r, __shfl_xor(r, 2));
        r = __fadd_rn(r, __shfl_xor(r, 4));
        p4[b] = r;
    }
    float s2 = __fadd_rn(__fadd_rn(p4[0], p4[1]), __fadd_rn(p4[2], p4[3]));
    if (lane == 0) {
        int b = g / N_NODES, loc = g % N_NODES;
        int r = loc / 56, c = loc % 56;
        int cls = (r & 1) * 2 + (c & 1);
        int m = (r >> 1) * 28 + (c >> 1);
        norms[g] = n;
        sq[(size_t)(b * 4 + cls) * 784 + m] = s2;
    }
}

// ---- RP: OpenBLAS-sgemm replica (sequential-k f32 FMA) + ref's f32 chain ----
__global__ __launch_bounds__(512, 4) void rp_gemm(const float* __restrict__ pe,
                                                  float* __restrict__ RP) {
    int brow = blockIdx.y * 64, bcol = blockIdx.x * 64;
    __shared__ float As[64][36], Bs[64][36];
    int t = threadIdx.x;                 // 0..511
    int tx = t & 15, ty = t >> 4;        // tx 0..15, ty 0..31
    float acc[2][4] = {{0.f}};
    for (int k0 = 0; k0 < DIMF; k0 += 32) {
        __syncthreads();
        {
            int m = t >> 3, kq = t & 7;  // 512 = 64 rows x 8 quads
            float4 v = make_float4(0.f, 0.f, 0.f, 0.f);
            int rowi = brow + m;
            if (rowi < 784) v = *(const float4*)(pe + (size_t)rowi * DIMF + k0 + kq * 4);
            *(float4*)&As[m][kq * 4] = v;
            float4 w = make_float4(0.f, 0.f, 0.f, 0.f);
            int coli = bcol + m;
            if (coli < 784) w = *(const float4*)(pe + (size_t)coli * DIMF + k0 + kq * 4);
            *(float4*)&Bs[m][kq * 4] = w;
        }
        __syncthreads();
        #pragma unroll 4
        for (int k = 0; k < 32; ++k) {          // ascending k, single FMA chain
            float ra[2], rb[4];
            #pragma unroll
            for (int ii = 0; ii < 2; ++ii) ra[ii] = As[ty + 32 * ii][k];
            #pragma unroll
            for (int jj = 0; jj < 4; ++jj) rb[jj] = Bs[tx + 16 * jj][k];
            #pragma unroll
            for (int ii = 0; ii < 2; ++ii)
                #pragma unroll
                for (int jj = 0; jj < 4; ++jj)
                    acc[ii][jj] = __fmaf_rn(ra[ii], rb[jj], acc[ii][jj]);
        }
    }
    #pragma unroll
    for (int ii = 0; ii < 2; ++ii) {
        int i = brow + ty + 32 * ii;
        if (i >= 784) continue;
        #pragma unroll
        for (int jj = 0; jj < 4; ++jj) {
            int j = bcol + tx + 16 * jj;
            if (j >= 784) continue;
            float X = acc[ii][jj];
            float num = __fmul_rn(2.0f, X);         // np: 2.0 * M
            float q = __fdiv_rn(num, 384.0f);       // np: / DIM
            RP[(size_t)i * 784 + j] = -q;           // np: unary negate
        }
    }
}

// ---- dist: np.einsum replica — 4-lane SSE mul+add partials, hadd tree -------
// Upper-triangle tiles only (x = tri index), mirror store; z = plane index.
__global__ __launch_bounds__(256) void dist_gemm(const float* __restrict__ x,
                                                 const float* __restrict__ norms,
                                                 const float* __restrict__ sq,
                                                 const float* __restrict__ RP,
                                                 float* __restrict__ dist, int bo) {
    int z = blockIdx.z;
    int b = bo + (z >> 2), cls = z & 3;
    // decode triangle index -> (by, bx) with bx >= by, 13x13 tile grid
    int rem = blockIdx.x, by = 0;
    #pragma unroll 1
    while (rem >= 13 - by) { rem -= 13 - by; ++by; }
    int bx = by + rem;
    int brow = by * 64, bcol = bx * 64;
    int oh = cls >> 1, ow = cls & 1;
    __shared__ float As[64][36], Bs[64][36];
    int t = threadIdx.x;
    int tx = t & 15, ty = t >> 4;
    float4 acc[4][4];
    #pragma unroll
    for (int ii = 0; ii < 4; ++ii)
        #pragma unroll
        for (int jj = 0; jj < 4; ++jj) acc[ii][jj] = make_float4(0.f, 0.f, 0.f, 0.f);
    for (int k0 = 0; k0 < DIMF; k0 += 32) {
        __syncthreads();
        #pragma unroll
        for (int p = 0; p < 2; ++p) {
            int f = t + 256 * p;
            int m = f >> 3, kq = f & 7;
            {
                int rowi = brow + m;
                float4 v = make_float4(0.f, 0.f, 0.f, 0.f);
                if (rowi < 784) {
                    int g = b * N_NODES + (oh + 2 * (rowi / 28)) * 56 + (ow + 2 * (rowi % 28));
                    float4 a = *(const float4*)(x + (size_t)g * DIMF + k0 + kq * 4);
                    float n = norms[g];
                    v.x = __fdiv_rn(a.x, n); v.y = __fdiv_rn(a.y, n);
                    v.z = __fdiv_rn(a.z, n); v.w = __fdiv_rn(a.w, n);   // = np xn bits
                }
                *(float4*)&As[m][kq * 4] = v;
            }
            {
                int coli = bcol + m;
                float4 v = make_float4(0.f, 0.f, 0.f, 0.f);
                if (coli < 784) {
                    int g = b * N_NODES + (oh + 2 * (coli / 28)) * 56 + (ow + 2 * (coli % 28));
                    float4 a = *(const float4*)(x + (size_t)g * DIMF + k0 + kq * 4);
                    float n = norms[g];
                    v.x = __fdiv_rn(a.x, n); v.y = __fdiv_rn(a.y, n);
                    v.z = __fdiv_rn(a.z, n); v.w = __fdiv_rn(a.w, n);
                }
                *(float4*)&Bs[m][kq * 4] = v;
            }
        }
        __syncthreads();
        // np.einsum f32 contig SIMD: lane l accumulates k = 4i+l, mul then add
        #pragma unroll 2
        for (int k4 = 0; k4 < 32; k4 += 4) {
            float4 ra[4], rb[4];
            #pragma unroll
            for (int ii = 0; ii < 4; ++ii) ra[ii] = *(float4*)&As[ty + 16 * ii][k4];
            #pragma unroll
            for (int jj = 0; jj < 4; ++jj) rb[jj] = *(float4*)&Bs[tx + 16 * jj][k4];
            #pragma unroll
            for (int ii = 0; ii < 4; ++ii)
                #pragma unroll
                for (int jj = 0; jj < 4; ++jj) {
                    acc[ii][jj].x = __fadd_rn(acc[ii][jj].x, __fmul_rn(ra[ii].x, rb[jj].x));
                    acc[ii][jj].y = __fadd_rn(acc[ii][jj].y, __fmul_rn(ra[ii].y, rb[jj].y));
                    acc[ii][jj].z = __fadd_rn(acc[ii][jj].z, __fmul_rn(ra[ii].z, rb[jj].z));
                    acc[ii][jj].w = __fadd_rn(acc[ii][jj].w, __fmul_rn(ra[ii].w, rb[jj].w));
                }
        }
    }
    int sqb = (b * 4 + cls) * 784;
    float* plane = dist + (size_t)z * 784 * 784;
    bool mirror = (bx != by);
    #pragma unroll
    for (int ii = 0; ii < 4; ++ii) {
        int i = brow + ty + 16 * ii;
        if (i >= 784) continue;
        float sqi = sq[sqb + i];
        #pragma unroll
        for (int jj = 0; jj < 4; ++jj) {
            int j = bcol + tx + 16 * jj;
            if (j >= 784) continue;
            float4 a = acc[ii][jj];
            // SSE3 hadd tree: (p0+p1) + (p2+p3)
            float X  = __fadd_rn(__fadd_rn(a.x, a.y), __fadd_rn(a.z, a.w));
            float t1 = __fadd_rn(sqi, sq[sqb + j]);            // sq_i + sq_j
            float pd = __fsub_rn(t1, __fmul_rn(2.0f, X));      // - 2*dot
            float v  = __fadd_rn(pd, RP[(size_t)i * 784 + j]); // + rp
            if (i == j) v = __fadd_rn(v, 100000.0f);           // diag add INF
            plane[(size_t)i * 784 + j] = v;
            if (mirror) plane[(size_t)j * 784 + i] = v;        // bitwise-equal mirror
        }
    }
}

// ---- per-row exact top-10, wave-per-row (no LDS, no barriers) ---------------
__global__ __launch_bounds__(256) void topk_kernel(const float* __restrict__ dist,
                                                   int* __restrict__ out, int bo) {
    int y = blockIdx.y;
    int b = bo + (y >> 2), cls = y & 3;
    int i = blockIdx.x * 4 + (threadIdx.x >> 6);   // row 0..783
    int lane = threadIdx.x & 63;
    const float* row = dist + (size_t)y * 784 * 784 + (size_t)i * 784;
    unsigned long long k[10];
    #pragma unroll
    for (int q = 0; q < 10; ++q) k[q] = 0xFFFFFFFFFFFFFFFFull;
    #pragma unroll
    for (int it = 0; it < 13; ++it) {
        int j = lane + it * 64;
        if (j < 784) {
            float v = row[j];
            unsigned u = __float_as_uint(v);
            u = (u & 0x80000000u) ? ~u : (u | 0x80000000u);   // order-preserving map
            unsigned long long key = ((unsigned long long)u << 32) | (unsigned)j;
            if (key < k[9]) {
                k[9] = key;                                  // insert + bubble up
                #pragma unroll
                for (int q = 9; q >= 1; --q) {
                    unsigned long long a = k[q - 1], c = k[q];
                    bool sw = (c < a);
                    k[q - 1] = sw ? c : a;
                    k[q]     = sw ? a : c;
                }
            }
        }
    }
    int oh = cls >> 1, ow = cls & 1;
    int gi = b * N_NODES + (oh + 2 * (i / 28)) * 56 + (ow + 2 * (i % 28));
    #pragma unroll
    for (int kk = 0; kk < 10; ++kk) {
        unsigned long long m = k[0];
        #pragma unroll
        for (int off = 32; off > 0; off >>= 1) {
            unsigned long long o = __shfl_xor(m, off);       // all lanes get min
            m = (o < m) ? o : m;
        }
        bool win = (k[0] == m);                              // unique (idx in key)
        #pragma unroll
        for (int q = 0; q < 9; ++q) k[q] = win ? k[q + 1] : k[q];
        k[9] = win ? 0xFFFFFFFFFFFFFFFFull : k[9];
        if (lane == 0) {
            int j = (int)(m & 0xFFFFFFFFull);
            int gj = b * N_NODES + (oh + 2 * (j / 28)) * 56 + (ow + 2 * (j % 28));
            size_t e = ((size_t)gi * 10 + kk) * 2;
            out[e] = gj;       // neighbor (already batch-offset)
            out[e + 1] = gi;   // source
        }
    }
}

extern "C" void kernel_launch(void* const* d_in, const int* in_sizes, int n_in,
                              void* d_out, int out_size, void* d_ws, size_t ws_size,
                              hipStream_t stream) {
    const float* x = (const float*)d_in[0];
    int* out = (int*)d_out;
    char* base = (char*)d_ws;
    float* norms = (float*)(base);
    float* sq    = (float*)(base + 100352);
    float* pe    = (float*)(base + 200704);
    float* RP    = (float*)(base + 1404928);
    float* dist  = (float*)(base + 3863552);

    // batch as many b-iterations as the workspace can hold dist slabs for
    const size_t fixed = 3863552, slab = 9834496;
    size_t avail = (ws_size > fixed) ? (ws_size - fixed) : slab;
    int fit = (int)(avail / slab);
    int nbatch = (fit >= 8) ? 8 : (fit >= 4) ? 4 : (fit >= 2) ? 2 : 1;

    pe_kernel<<<dim3(784), dim3(96), 0, stream>>>(pe);
    norm_sq_kernel<<<dim3(784), dim3(256), 0, stream>>>(x, norms, sq);
    rp_gemm<<<dim3(13, 13), dim3(512), 0, stream>>>(pe, RP);
    for (int bo = 0; bo < NB; bo += nbatch) {
        dist_gemm<<<dim3(91, 1, 4 * nbatch), dim3(256), 0, stream>>>(x, norms, sq, RP, dist, bo);
        topk_kernel<<<dim3(196, 4 * nbatch), dim3(256), 0, stream>>>(dist, out, bo);
    }
}